// Round 1
// baseline (314.093 us; speedup 1.0000x reference)
//
#include <hip/hip_runtime.h>
#include <hip/hip_fp16.h>

// Problem: EfficientAttention  B=4, S=4096, D=1024, fp32 in/out.
//   Q = x@Wq^T + bq ; K = x@Wk^T + bk ; V = x@Wv^T + bv
//   KV[b,d,e] = (1/32) * sum_s K[b,s,d] V[b,s,e]
//   E[b,s,e]  = sum_d Q[b,s,d] KV[b,d,e]
// All contractions run as fp16-MFMA NT GEMMs (C = A[M,K] @ B[N,K]^T), fp32 accum.

#define BATCH 4
#define SEQ   4096
#define DM    1024

typedef _Float16 h8 __attribute__((ext_vector_type(8)));
typedef _Float16 h4 __attribute__((ext_vector_type(4)));
typedef float    f4 __attribute__((ext_vector_type(4)));

__device__ inline void gload_lds16(const _Float16* g, _Float16* l) {
    __builtin_amdgcn_global_load_lds(
        (const __attribute__((address_space(1))) void*)g,
        (__attribute__((address_space(3))) void*)l,
        16, 0, 0);
}

__global__ __launch_bounds__(256) void cvt_f32_f16(
    const float* __restrict__ s, _Float16* __restrict__ d, long n)
{
    long i = ((long)blockIdx.x * 256 + threadIdx.x) * 4;
    const long stride = (long)gridDim.x * 256 * 4;
    for (; i < n; i += stride) {
        f4 v = *(const f4*)(s + i);
        h4 h = { (_Float16)v.x, (_Float16)v.y, (_Float16)v.z, (_Float16)v.w };
        *(h4*)(d + i) = h;
    }
}

// Generic NT GEMM: C[M,N] = alpha * (A[M,K] @ B[N,K]^T) + bias
// BIAS: 0 none, 1 per-column, 2 per-row.  OutT: _Float16 or float.
// 128x128 tile, BK=64, 256 threads = 4 waves (2x2), each wave 64x64 (4x4 MFMA frags).
// LDS tiles [128][64] fp16, XOR-swizzled on 16B slots: phys_slot = slot ^ (row & 7).
// global_load_lds writes linearly -> inverse swizzle applied to the GLOBAL source
// address (rule: both-sides-or-neither), reads apply the same swizzle.
template<typename OutT, int BIAS>
__global__ __launch_bounds__(256) void gemm_nt(
    const _Float16* __restrict__ A, const _Float16* __restrict__ B,
    OutT* __restrict__ C, const float* __restrict__ bias,
    int M, int N, int K, long aStride, long bStride, long cStride, float alpha)
{
    __shared__ _Float16 As[128 * 64];
    __shared__ _Float16 Bs[128 * 64];

    const int z = blockIdx.z;
    A += (long)z * aStride;
    B += (long)z * bStride;
    C += (long)z * cStride;

    const int tileM = blockIdx.y * 128;
    const int tileN = blockIdx.x * 128;
    const int tid   = threadIdx.x;
    const int lane  = tid & 63;
    const int wave  = tid >> 6;
    const int wm    = (wave >> 1) * 64;   // wave row offset in tile
    const int wn    = (wave & 1) * 64;    // wave col offset in tile

    // staging decomposition: per issue i (4 issues), unit U=i*256+tid covers
    // (row = U>>3, phys 16B slot = U&7) of the [128][64]-half tile.
    const int srow  = tid >> 3;  // 0..31 within a 32-row group
    const int sslot = tid & 7;   // physical slot this thread's 16B lands in

    f4 acc[4][4] = {};

    const int arow = lane & 15;
    const int kg   = lane >> 4;  // 0..3 : k-subgroup of the MFMA fragment

    for (int k0 = 0; k0 < K; k0 += 64) {
        #pragma unroll
        for (int i = 0; i < 4; ++i) {
            const int row   = i * 32 + srow;
            const int gslot = sslot ^ (row & 7);   // logical slot to fetch
            gload_lds16(&A[(long)(tileM + row) * K + k0 + gslot * 8],
                        &As[row * 64 + sslot * 8]);
            gload_lds16(&B[(long)(tileN + row) * K + k0 + gslot * 8],
                        &Bs[row * 64 + sslot * 8]);
        }
        __syncthreads();   // compiler drains vmcnt before s_barrier

        #pragma unroll
        for (int kk = 0; kk < 64; kk += 32) {
            h8 af[4], bf[4];
            #pragma unroll
            for (int m = 0; m < 4; ++m) {
                const int r    = wm + m * 16 + arow;
                const int slot = (kk >> 3) + kg;
                af[m] = *(const h8*)&As[r * 64 + ((slot ^ (r & 7)) << 3)];
            }
            #pragma unroll
            for (int n = 0; n < 4; ++n) {
                const int r    = wn + n * 16 + arow;
                const int slot = (kk >> 3) + kg;
                bf[n] = *(const h8*)&Bs[r * 64 + ((slot ^ (r & 7)) << 3)];
            }
            #pragma unroll
            for (int m = 0; m < 4; ++m)
                #pragma unroll
                for (int n = 0; n < 4; ++n)
                    acc[m][n] = __builtin_amdgcn_mfma_f32_16x16x32_f16(
                        af[m], bf[n], acc[m][n], 0, 0, 0);
        }
        __syncthreads();
    }

    // epilogue: C/D layout col = lane&15, row = (lane>>4)*4 + j  (m89-verified)
    #pragma unroll
    for (int m = 0; m < 4; ++m) {
        #pragma unroll
        for (int n = 0; n < 4; ++n) {
            const int col = tileN + wn + n * 16 + arow;
            #pragma unroll
            for (int j = 0; j < 4; ++j) {
                const int row = tileM + wm + m * 16 + (lane >> 4) * 4 + j;
                float v = acc[m][n][j] * alpha;
                if (BIAS == 1) v += bias[col];
                if (BIAS == 2) v += bias[row];
                C[(long)row * N + col] = (OutT)v;
            }
        }
    }
}

extern "C" void kernel_launch(void* const* d_in, const int* in_sizes, int n_in,
                              void* d_out, int out_size, void* d_ws, size_t ws_size,
                              hipStream_t stream)
{
    const float* x  = (const float*)d_in[0];
    const float* Wq = (const float*)d_in[1];
    const float* bq = (const float*)d_in[2];
    const float* Wk = (const float*)d_in[3];
    const float* bk = (const float*)d_in[4];
    const float* Wv = (const float*)d_in[5];
    const float* bv = (const float*)d_in[6];
    float* out = (float*)d_out;

    const long MD = (long)BATCH * SEQ * DM;   // 16,777,216
    const long DD = (long)DM * DM;            // 1,048,576
    const long DS = (long)DM * SEQ;           // 4,194,304

    // workspace layout (fp16): xh | Qh | KVt | Wq | Wk | Wv  -> ~78 MB
    _Float16* xh   = (_Float16*)d_ws;
    _Float16* Qh   = xh + MD;
    _Float16* KVth = Qh + MD;                 // [B][e][d]
    _Float16* Wqh  = KVth + (long)BATCH * DD;
    _Float16* Wkh  = Wqh + DD;
    _Float16* Wvh  = Wkh + DD;
    // Kt/Vt ([B][d][s], fp16, 32MB each) live in d_out scratch; both are fully
    // consumed by the KV GEMM before the E GEMM overwrites d_out.
    _Float16* Kth  = (_Float16*)d_out;
    _Float16* Vth  = Kth + MD;

    // 1) fp32 -> fp16 conversions
    cvt_f32_f16<<<4096, 256, 0, stream>>>(x,  xh,  MD);
    cvt_f32_f16<<<1024, 256, 0, stream>>>(Wq, Wqh, DD);
    cvt_f32_f16<<<1024, 256, 0, stream>>>(Wk, Wkh, DD);
    cvt_f32_f16<<<1024, 256, 0, stream>>>(Wv, Wvh, DD);

    // 2) Q[m,e] = x[m,:]·Wq[e,:] + bq[e]   (col bias)  -> Qh [16384,1024]
    gemm_nt<_Float16, 1><<<dim3(DM / 128, (BATCH * SEQ) / 128, 1), 256, 0, stream>>>(
        xh, Wqh, Qh, bq, BATCH * SEQ, DM, DM, 0, 0, 0, 1.0f);

    // 3) Kt[b][d,s] = Wk[d,:]·x[b,s,:] + bk[d]   (row bias) -> [1024,4096] per batch
    gemm_nt<_Float16, 2><<<dim3(SEQ / 128, DM / 128, BATCH), 256, 0, stream>>>(
        Wkh, xh, Kth, bk, DM, SEQ, DM, 0, (long)SEQ * DM, DS, 1.0f);
    gemm_nt<_Float16, 2><<<dim3(SEQ / 128, DM / 128, BATCH), 256, 0, stream>>>(
        Wvh, xh, Vth, bv, DM, SEQ, DM, 0, (long)SEQ * DM, DS, 1.0f);

    // 4) KVt[b][e,d] = (1/32) * Vt[b][e,:]·Kt[b][d,:]  (contract over s=4096)
    gemm_nt<_Float16, 0><<<dim3(DM / 128, DM / 128, BATCH), 256, 0, stream>>>(
        Vth, Kth, KVth, nullptr, DM, DM, SEQ, DS, DS, DD, 0.03125f);

    // 5) E[b][s,e] = Q[b][s,:]·KVt[b][e,:]  -> fp32 out
    gemm_nt<float, 0><<<dim3(DM / 128, SEQ / 128, BATCH), 256, 0, stream>>>(
        Qh, KVth, out, nullptr, SEQ, DM, DM, (long)SEQ * DM, DD, (long)SEQ * DM, 1.0f);
}

// Round 4
// 245.181 us; speedup vs baseline: 1.2811x; 1.2811x over previous
//
#include <hip/hip_runtime.h>
#include <hip/hip_fp16.h>

// EfficientAttention  B=4, S=4096, D=1024, fp32 in/out.
// Algebraic restructure:
//   G[b]   = x[b]^T x[b]                      (Gram, K=4096, split-K=4, partials in d_out)
//   KVt[b] = (1/32)(Wv G Wk^T + bk ox u2 + bv ox w)   [e][d] layout
//   Rt[b]  = KVt Wq^T                          [e][i]
//   E[b]   = x Rt^T + c[b]                     (c[e] = sum_d bq[d] KVt[e,d])
// All GEMMs are fp16-MFMA NT (C[m,n] = sum_k A[m,k]B[n,k]), fp32 accum.

#define BATCH 4
#define SEQ   4096
#define DM    1024

typedef _Float16 h8 __attribute__((ext_vector_type(8)));
typedef _Float16 h4 __attribute__((ext_vector_type(4)));
typedef float    f4 __attribute__((ext_vector_type(4)));

__device__ inline void gload_lds16(const _Float16* g, _Float16* l) {
    __builtin_amdgcn_global_load_lds(
        (const __attribute__((address_space(1))) void*)g,
        (__attribute__((address_space(3))) void*)l,
        16, 0, 0);
}

// plain fp32 -> fp16 convert
__global__ __launch_bounds__(256) void cvt_f32_f16(
    const float* __restrict__ s, _Float16* __restrict__ d, long n)
{
    long i = ((long)blockIdx.x * 256 + threadIdx.x) * 4;
    const long stride = (long)gridDim.x * 256 * 4;
    for (; i < n; i += stride) {
        f4 v = *(const f4*)(s + i);
        h4 h = { (_Float16)v.x, (_Float16)v.y, (_Float16)v.z, (_Float16)v.w };
        *(h4*)(d + i) = h;
    }
}

// fp32 [Z][R][C] -> fp16 transposed [Z][C][R] (dstT), optionally also row-major fp16 (dstRM).
// 64x64 LDS tile; fp32 tile [64][65] -> transposed reads are 2-way bank aliased (free).
template<bool WRITE_RM>
__global__ __launch_bounds__(256) void cvt_transpose(
    const float* __restrict__ src, _Float16* __restrict__ dstT,
    _Float16* __restrict__ dstRM, int R, int C)
{
    __shared__ float tile[64][65];
    const long zoff = (long)blockIdx.z * R * C;
    src += zoff; dstT += zoff;
    if (WRITE_RM) dstRM += zoff;
    const int r0 = blockIdx.y * 64;
    const int c0 = blockIdx.x * 64;
    const int t  = threadIdx.x;
    const int tr = t >> 4;         // 0..15
    const int tc = (t & 15) * 4;   // 0..60
    #pragma unroll
    for (int i = 0; i < 4; ++i) {
        const int r = tr + i * 16;
        f4 v = *(const f4*)&src[(long)(r0 + r) * C + c0 + tc];
        tile[r][tc + 0] = v.x; tile[r][tc + 1] = v.y;
        tile[r][tc + 2] = v.z; tile[r][tc + 3] = v.w;
        if (WRITE_RM) {
            h4 h = { (_Float16)v.x, (_Float16)v.y, (_Float16)v.z, (_Float16)v.w };
            *(h4*)&dstRM[(long)(r0 + r) * C + c0 + tc] = h;
        }
    }
    __syncthreads();
    #pragma unroll
    for (int i = 0; i < 4; ++i) {
        const int c = tr + i * 16;  // column of src = row of dstT
        h4 h = { (_Float16)tile[tc + 0][c], (_Float16)tile[tc + 1][c],
                 (_Float16)tile[tc + 2][c], (_Float16)tile[tc + 3][c] };
        *(h4*)&dstT[(long)(c0 + c) * R + r0 + tc] = h;
    }
}

// xs[b*DM + d] = sum_s xt[b][d][s]   (one wave per row)
__global__ __launch_bounds__(256) void rowsum_xt(
    const _Float16* __restrict__ xt, float* __restrict__ xs)
{
    const int gw   = blockIdx.x * 4 + (threadIdx.x >> 6);
    const int lane = threadIdx.x & 63;
    const _Float16* row = xt + (long)gw * SEQ;
    float s = 0.f;
    #pragma unroll
    for (int i = 0; i < SEQ; i += 512) {
        h8 v = *(const h8*)&row[i + lane * 8];
        #pragma unroll
        for (int j = 0; j < 8; ++j) s += (float)v[j];
    }
    #pragma unroll
    for (int off = 32; off; off >>= 1) s += __shfl_down(s, off);
    if (lane == 0) xs[gw] = s;
}

// out[b*1024+o] = sum_k W[b*wZ + o*1024 + k] * vec[b*vZ + k]  (+ addScale*addV[o])
// one wave per output; K fixed = 1024
__global__ __launch_bounds__(256) void gemv_k1024(
    const _Float16* __restrict__ W, long wZ,
    const float* __restrict__ vec, long vZ,
    const float* __restrict__ addV, float addScale,
    float* __restrict__ out)
{
    const int gw   = blockIdx.x * 4 + (threadIdx.x >> 6);
    const int b    = gw >> 10;
    const int o    = gw & 1023;
    const int lane = threadIdx.x & 63;
    const _Float16* wr = W + b * wZ + (long)o * 1024;
    const float*    v  = vec + b * vZ;
    float s = 0.f;
    #pragma unroll
    for (int i = 0; i < 2; ++i) {
        const int k = i * 512 + lane * 8;
        h8 wv = *(const h8*)&wr[k];
        f4 v0 = *(const f4*)&v[k];
        f4 v1 = *(const f4*)&v[k + 4];
        s += (float)wv[0] * v0.x + (float)wv[1] * v0.y +
             (float)wv[2] * v0.z + (float)wv[3] * v0.w +
             (float)wv[4] * v1.x + (float)wv[5] * v1.y +
             (float)wv[6] * v1.z + (float)wv[7] * v1.w;
    }
    #pragma unroll
    for (int off = 32; off; off >>= 1) s += __shfl_down(s, off);
    if (lane == 0) out[gw] = s + (addV ? addScale * addV[o] : 0.f);
}

// Gh[b][i][j] = (1/32) * sum_{k<4} parts[(b*4+k)][i][j]
__global__ __launch_bounds__(256) void reduce_g(
    const float* __restrict__ parts, _Float16* __restrict__ Gh)
{
    const long DD_ = (long)DM * DM;
    long i = ((long)blockIdx.x * 256 + threadIdx.x) * 4;   // over BATCH*DD
    const long b = i >> 20;
    const long r = i & (DD_ - 1);
    const float* p = parts + b * 4 * DD_ + r;
    f4 a = *(const f4*)&p[0];
    a += *(const f4*)&p[DD_];
    a += *(const f4*)&p[2 * DD_];
    a += *(const f4*)&p[3 * DD_];
    const float sc = 0.03125f;
    h4 h = { (_Float16)(a.x * sc), (_Float16)(a.y * sc),
             (_Float16)(a.z * sc), (_Float16)(a.w * sc) };
    *(h4*)&Gh[i] = h;
}

// Generic NT GEMM: C[m,n] = alpha*sum_k A[m,k]B[n,k] + bias
// BIAS: 0 none; 1: + bc1[col]; 3: + beta*(bc1[col]*br1[row] + bc2[col]*br2[row])
// z decomposition: zb = z/sk (batch), zk = z%sk (K-slice).
template<typename OutT, int BIAS>
__global__ __launch_bounds__(256) void gemm_nt(
    const _Float16* __restrict__ A, const _Float16* __restrict__ B,
    OutT* __restrict__ C,
    int M, int N, int K, int lda, int ldb, int ldc,
    long aZ, long bZ, long cZ, int sk, long aK, long bK,
    const float* __restrict__ bc1, long bc1Z,
    const float* __restrict__ br1, long br1Z,
    const float* __restrict__ bc2, long bc2Z,
    const float* __restrict__ br2, long br2Z,
    float alpha, float beta)
{
    __shared__ _Float16 As[128 * 64];
    __shared__ _Float16 Bs[128 * 64];

    const int z  = blockIdx.z;
    const int zb = z / sk;
    const int zk = z - zb * sk;
    A += (long)zb * aZ + (long)zk * aK;
    B += (long)zb * bZ + (long)zk * bK;
    C += (long)z * cZ;
    const float* pc1 = nullptr; const float* pr1 = nullptr;
    const float* pc2 = nullptr; const float* pr2 = nullptr;
    if (BIAS == 1) { pc1 = bc1 + (long)zb * bc1Z; }
    if (BIAS == 3) {
        pc1 = bc1 + (long)zb * bc1Z; pr1 = br1 + (long)zb * br1Z;
        pc2 = bc2 + (long)zb * bc2Z; pr2 = br2 + (long)zb * br2Z;
    }

    const int tileM = blockIdx.y * 128;
    const int tileN = blockIdx.x * 128;
    const int tid   = threadIdx.x;
    const int lane  = tid & 63;
    const int wave  = tid >> 6;
    const int wm    = (wave >> 1) * 64;
    const int wn    = (wave & 1) * 64;

    const int srow  = tid >> 3;
    const int sslot = tid & 7;

    f4 acc[4][4] = {};

    const int arow = lane & 15;
    const int kg   = lane >> 4;

    for (int k0 = 0; k0 < K; k0 += 64) {
        #pragma unroll
        for (int i = 0; i < 4; ++i) {
            const int row   = i * 32 + srow;
            const int gslot = sslot ^ (row & 7);
            gload_lds16(&A[(long)(tileM + row) * lda + k0 + gslot * 8],
                        &As[row * 64 + sslot * 8]);
            gload_lds16(&B[(long)(tileN + row) * ldb + k0 + gslot * 8],
                        &Bs[row * 64 + sslot * 8]);
        }
        __syncthreads();

        #pragma unroll
        for (int kk = 0; kk < 64; kk += 32) {
            h8 af[4], bf[4];
            #pragma unroll
            for (int m = 0; m < 4; ++m) {
                const int r    = wm + m * 16 + arow;
                const int slot = (kk >> 3) + kg;
                af[m] = *(const h8*)&As[r * 64 + ((slot ^ (r & 7)) << 3)];
            }
            #pragma unroll
            for (int n = 0; n < 4; ++n) {
                const int r    = wn + n * 16 + arow;
                const int slot = (kk >> 3) + kg;
                bf[n] = *(const h8*)&Bs[r * 64 + ((slot ^ (r & 7)) << 3)];
            }
            #pragma unroll
            for (int m = 0; m < 4; ++m)
                #pragma unroll
                for (int n = 0; n < 4; ++n)
                    acc[m][n] = __builtin_amdgcn_mfma_f32_16x16x32_f16(
                        af[m], bf[n], acc[m][n], 0, 0, 0);
        }
        __syncthreads();
    }

    #pragma unroll
    for (int m = 0; m < 4; ++m) {
        #pragma unroll
        for (int n = 0; n < 4; ++n) {
            const int col = tileN + wn + n * 16 + arow;
            #pragma unroll
            for (int j = 0; j < 4; ++j) {
                const int row = tileM + wm + m * 16 + (lane >> 4) * 4 + j;
                float v = acc[m][n][j] * alpha;
                if (BIAS == 1) v += pc1[col];
                if (BIAS == 3) v += beta * (pc1[col] * pr1[row] + pc2[col] * pr2[row]);
                C[(long)row * ldc + col] = (OutT)v;
            }
        }
    }
}

extern "C" void kernel_launch(void* const* d_in, const int* in_sizes, int n_in,
                              void* d_out, int out_size, void* d_ws, size_t ws_size,
                              hipStream_t stream)
{
    const float* x  = (const float*)d_in[0];
    const float* Wq = (const float*)d_in[1];
    const float* bq = (const float*)d_in[2];
    const float* Wk = (const float*)d_in[3];
    const float* bk = (const float*)d_in[4];
    const float* Wv = (const float*)d_in[5];
    const float* bv = (const float*)d_in[6];
    float* out = (float*)d_out;

    const long DD = (long)DM * DM;            // 1.05M
    const long DS = (long)DM * SEQ;           // 4.19M (per-batch x elems)

    // ws layout:
    // [xh 32MB][xtRegion 32MB][Wqt 2MB][Wkh 2MB][Wvh 2MB][xs|u2|w|cv 64KB] ~ 70MB
    // xtRegion holds xt until G-GEMM+rowsum consume it; then reused for Gh|Ph|KVth|Rth.
    char* base = (char*)d_ws;
    _Float16* xh   = (_Float16*)base;                       // 16M fp16
    _Float16* xt   = (_Float16*)(base + 32l * 1024 * 1024); // 16M fp16
    _Float16* Gh   = xt;                                    // 4M fp16 (after xt dead)
    _Float16* Ph   = xt + 4l * 1024 * 1024;
    _Float16* KVth = xt + 8l * 1024 * 1024;
    _Float16* Rth  = xt + 12l * 1024 * 1024;
    _Float16* Wqt  = (_Float16*)(base + 64l * 1024 * 1024);
    _Float16* Wkh  = Wqt + DD;
    _Float16* Wvh  = Wkh + DD;
    float*    xs   = (float*)(Wvh + DD);                    // [4][1024]
    float*    u2   = xs + 4 * 1024;
    float*    w    = u2 + 4 * 1024;
    float*    cv   = w + 4 * 1024;
    float*    parts = (float*)d_out;                        // [16][1024][1024] fp32 scratch

    // 1) converts / transposes
    cvt_transpose<true ><<<dim3(16, 64, 4), 256, 0, stream>>>(x,  xt,  xh, SEQ, DM);
    cvt_transpose<false><<<dim3(16, 16, 1), 256, 0, stream>>>(Wq, Wqt, nullptr, DM, DM);
    cvt_f32_f16<<<1024, 256, 0, stream>>>(Wk, Wkh, DD);
    cvt_f32_f16<<<1024, 256, 0, stream>>>(Wv, Wvh, DD);

    // 2) xs[b][i] = sum_s x[b][s][i]  (rowsum of xt)
    rowsum_xt<<<1024, 256, 0, stream>>>(xt, xs);

    // 3) u2[b][e] = xs.Wv[e] + 4096*bv[e] ;  w[b][d] = xs.Wk[d]
    gemv_k1024<<<1024, 256, 0, stream>>>(Wvh, 0, xs, 1024, bv, (float)SEQ, u2);
    gemv_k1024<<<1024, 256, 0, stream>>>(Wkh, 0, xs, 1024, nullptr, 0.f, w);

    // 4) G split-K=4: parts[b*4+k] = xt[b](:,k-slice) @ xt[b](:,k-slice)^T
    gemm_nt<float, 0><<<dim3(8, 8, 16), 256, 0, stream>>>(
        xt, xt, parts, DM, DM, 1024, SEQ, SEQ, DM,
        DS, DS, DD, 4, 1024, 1024,
        nullptr, 0, nullptr, 0, nullptr, 0, nullptr, 0, 1.0f, 0.f);

    // 5) Gh = (1/32)*sum parts   (writes into xt region; xt fully consumed)
    reduce_g<<<4096, 256, 0, stream>>>(parts, Gh);

    // 6) Ph[b][e][i] = sum_j Wv[e,j] * Gh[b][i,j]
    gemm_nt<_Float16, 0><<<dim3(8, 8, 4), 256, 0, stream>>>(
        Wvh, Gh, Ph, DM, DM, DM, DM, DM, DM,
        0, DD, DD, 1, 0, 0,
        nullptr, 0, nullptr, 0, nullptr, 0, nullptr, 0, 1.0f, 0.f);

    // 7) KVth[b][e][d] = sum_i Ph[e,i]Wk[d,i] + (1/32)(bk[d]*u2[b][e] + bv[e]*w[b][d])
    gemm_nt<_Float16, 3><<<dim3(8, 8, 4), 256, 0, stream>>>(
        Ph, Wkh, KVth, DM, DM, DM, DM, DM, DM,
        DD, 0, DD, 1, 0, 0,
        bk, 0, u2, 1024, w, 1024, bv, 0, 1.0f, 0.03125f);

    // 8) cv[b][e] = sum_d bq[d] * KVth[b][e][d]
    gemv_k1024<<<1024, 256, 0, stream>>>(KVth, DD, bq, 0, nullptr, 0.f, cv);

    // 9) Rth[b][e][i] = sum_d KVth[e,d] * Wqt[i,d]
    gemm_nt<_Float16, 0><<<dim3(8, 8, 4), 256, 0, stream>>>(
        KVth, Wqt, Rth, DM, DM, DM, DM, DM, DM,
        DD, 0, DD, 1, 0, 0,
        nullptr, 0, nullptr, 0, nullptr, 0, nullptr, 0, 1.0f, 0.f);

    // 10) E[b][s][e] = sum_i xh[s,i]*Rth[e,i] + cv[b][e]
    gemm_nt<float, 1><<<dim3(8, 32, 4), 256, 0, stream>>>(
        xh, Rth, out, SEQ, DM, DM, DM, DM, DM,
        DS, DD, DS, 1, 0, 0,
        cv, 1024, nullptr, 0, nullptr, 0, nullptr, 0, 1.0f, 0.f);
}

// Round 5
// 196.015 us; speedup vs baseline: 1.6024x; 1.2508x over previous
//
#include <hip/hip_runtime.h>
#include <hip/hip_fp16.h>

// EfficientAttention  B=4, S=4096, D=1024, fp32 in/out.
//   G[b]   = x[b]^T x[b]              (Gram, split-K=4, fp16 partials in d_out)
//   Gh     = (1/32) sum_k parts
//   Ph[b]  = Wv Gh[b]                 ; KVt[b] = Ph Wk^T + rank-1 bias terms
//   Rt[b]  = KVt Wq^T                 ; E[b]   = x Rt^T + cv[b]
// All GEMMs fp16-MFMA NT (C[m,n]=sum_k A[m,k]B[n,k]), fp32 accum.
// XCD-aware chunked block swizzle on all GEMMs (grids divisible by 8).

#define BATCH 4
#define SEQ   4096
#define DM    1024

typedef _Float16 h8 __attribute__((ext_vector_type(8)));
typedef _Float16 h4 __attribute__((ext_vector_type(4)));
typedef float    f4 __attribute__((ext_vector_type(4)));

__device__ inline void gload_lds16(const _Float16* g, _Float16* l) {
    __builtin_amdgcn_global_load_lds(
        (const __attribute__((address_space(1))) void*)g,
        (__attribute__((address_space(3))) void*)l,
        16, 0, 0);
}

// bijective XCD chunk swizzle: hw bid -> logical L. requires gridDim.x % 8 == 0.
__device__ inline int xcd_swz(int bid, int grid) {
    const int q = grid >> 3;
    return (bid & 7) * q + (bid >> 3);
}

// fp32 [Z][R][C] -> fp16 transposed [Z][C][R] (dstT), optionally also row-major fp16.
template<bool WRITE_RM>
__global__ __launch_bounds__(256) void cvt_transpose(
    const float* __restrict__ src, _Float16* __restrict__ dstT,
    _Float16* __restrict__ dstRM, int R, int C)
{
    __shared__ float tile[64][65];
    const long zoff = (long)blockIdx.z * R * C;
    src += zoff; dstT += zoff;
    if (WRITE_RM) dstRM += zoff;
    const int r0 = blockIdx.y * 64;
    const int c0 = blockIdx.x * 64;
    const int t  = threadIdx.x;
    const int tr = t >> 4;
    const int tc = (t & 15) * 4;
    #pragma unroll
    for (int i = 0; i < 4; ++i) {
        const int r = tr + i * 16;
        f4 v = *(const f4*)&src[(long)(r0 + r) * C + c0 + tc];
        tile[r][tc + 0] = v.x; tile[r][tc + 1] = v.y;
        tile[r][tc + 2] = v.z; tile[r][tc + 3] = v.w;
        if (WRITE_RM) {
            h4 h = { (_Float16)v.x, (_Float16)v.y, (_Float16)v.z, (_Float16)v.w };
            *(h4*)&dstRM[(long)(r0 + r) * C + c0 + tc] = h;
        }
    }
    __syncthreads();
    #pragma unroll
    for (int i = 0; i < 4; ++i) {
        const int c = tr + i * 16;
        h4 h = { (_Float16)tile[tc + 0][c], (_Float16)tile[tc + 1][c],
                 (_Float16)tile[tc + 2][c], (_Float16)tile[tc + 3][c] };
        *(h4*)&dstT[(long)(c0 + c) * R + r0 + tc] = h;
    }
}

// Wk, Wv -> fp16 in one launch (grid 2048: first 1024 blocks Wk, rest Wv)
__global__ __launch_bounds__(256) void cvt_pair(
    const float* __restrict__ s0, _Float16* __restrict__ d0,
    const float* __restrict__ s1, _Float16* __restrict__ d1)
{
    const int half = blockIdx.x >> 10;
    const long i = ((long)(blockIdx.x & 1023) * 256 + threadIdx.x) * 4;
    const float* s = half ? s1 : s0;
    _Float16*    d = half ? d1 : d0;
    f4 v = *(const f4*)(s + i);
    h4 h = { (_Float16)v.x, (_Float16)v.y, (_Float16)v.z, (_Float16)v.w };
    *(h4*)(d + i) = h;
}

// xs[b*DM + d] = sum_s xt[b][d][s]
__global__ __launch_bounds__(256) void rowsum_xt(
    const _Float16* __restrict__ xt, float* __restrict__ xs)
{
    const int gw   = blockIdx.x * 4 + (threadIdx.x >> 6);
    const int lane = threadIdx.x & 63;
    const _Float16* row = xt + (long)gw * SEQ;
    float s = 0.f;
    #pragma unroll
    for (int i = 0; i < SEQ; i += 512) {
        h8 v = *(const h8*)&row[i + lane * 8];
        #pragma unroll
        for (int j = 0; j < 8; ++j) s += (float)v[j];
    }
    #pragma unroll
    for (int off = 32; off; off >>= 1) s += __shfl_down(s, off);
    if (lane == 0) xs[gw] = s;
}

// dual gemv: gw<4096: u2[gw] = Wv[o,:].xs[b] + 4096*bv[o]; else w[gw-4096] = Wk[o,:].xs[b]
// u2 and w are contiguous (dst = u2 base, 8192 floats).
__global__ __launch_bounds__(256) void gemv_dual(
    const _Float16* __restrict__ Wvh, const _Float16* __restrict__ Wkh,
    const float* __restrict__ xs, const float* __restrict__ bv,
    float* __restrict__ dst)
{
    const int gw   = blockIdx.x * 4 + (threadIdx.x >> 6);
    const int half = gw >> 12;
    const int g    = gw & 4095;
    const int b    = g >> 10;
    const int o    = g & 1023;
    const int lane = threadIdx.x & 63;
    const _Float16* wr = (half ? Wkh : Wvh) + (long)o * 1024;
    const float*    v  = xs + b * 1024;
    float s = 0.f;
    #pragma unroll
    for (int i = 0; i < 2; ++i) {
        const int k = i * 512 + lane * 8;
        h8 wv = *(const h8*)&wr[k];
        f4 v0 = *(const f4*)&v[k];
        f4 v1 = *(const f4*)&v[k + 4];
        s += (float)wv[0] * v0.x + (float)wv[1] * v0.y +
             (float)wv[2] * v0.z + (float)wv[3] * v0.w +
             (float)wv[4] * v1.x + (float)wv[5] * v1.y +
             (float)wv[6] * v1.z + (float)wv[7] * v1.w;
    }
    #pragma unroll
    for (int off = 32; off; off >>= 1) s += __shfl_down(s, off);
    if (lane == 0) dst[gw] = s + (half ? 0.f : (float)SEQ * bv[o]);
}

// out[b*1024+o] = sum_k W[b*wZ + o*1024 + k] * vec[k]
__global__ __launch_bounds__(256) void gemv_k1024(
    const _Float16* __restrict__ W, long wZ,
    const float* __restrict__ vec, float* __restrict__ out)
{
    const int gw   = blockIdx.x * 4 + (threadIdx.x >> 6);
    const int b    = gw >> 10;
    const int o    = gw & 1023;
    const int lane = threadIdx.x & 63;
    const _Float16* wr = W + b * wZ + (long)o * 1024;
    float s = 0.f;
    #pragma unroll
    for (int i = 0; i < 2; ++i) {
        const int k = i * 512 + lane * 8;
        h8 wv = *(const h8*)&wr[k];
        f4 v0 = *(const f4*)&vec[k];
        f4 v1 = *(const f4*)&vec[k + 4];
        s += (float)wv[0] * v0.x + (float)wv[1] * v0.y +
             (float)wv[2] * v0.z + (float)wv[3] * v0.w +
             (float)wv[4] * v1.x + (float)wv[5] * v1.y +
             (float)wv[6] * v1.z + (float)wv[7] * v1.w;
    }
    #pragma unroll
    for (int off = 32; off; off >>= 1) s += __shfl_down(s, off);
    if (lane == 0) out[gw] = s;
}

// Gh[b][r..] = (1/32) * sum_{k<4} parts_h[(b*4+k)][r..]   (fp16 partials)
__global__ __launch_bounds__(256) void reduce_gh(
    const _Float16* __restrict__ parts, _Float16* __restrict__ Gh)
{
    const long DD_ = (long)DM * DM;
    const long i = ((long)blockIdx.x * 256 + threadIdx.x) * 8;   // over BATCH*DD
    const long b = i >> 20;
    const long r = i & (DD_ - 1);
    const _Float16* p = parts + b * 4 * DD_ + r;
    h8 v0 = *(const h8*)&p[0];
    h8 v1 = *(const h8*)&p[DD_];
    h8 v2 = *(const h8*)&p[2 * DD_];
    h8 v3 = *(const h8*)&p[3 * DD_];
    h8 o;
    #pragma unroll
    for (int j = 0; j < 8; ++j) {
        float s = (float)v0[j] + (float)v1[j] + (float)v2[j] + (float)v3[j];
        o[j] = (_Float16)(s * 0.03125f);
    }
    *(h8*)&Gh[i] = o;
}

// 128x128 NT GEMM, flat grid + XCD swizzle + split-K decode.
// BIAS: 0 none; 1: + bc1[col] (per zb)
template<typename OutT, int BIAS>
__global__ __launch_bounds__(256) void gemm_nt(
    const _Float16* __restrict__ A, const _Float16* __restrict__ B,
    OutT* __restrict__ C,
    int K, int lda, int ldb, int ldc, int tilesX, int perZ,
    long aZ, long bZ, long cZ, int sk, long aK, long bK,
    const float* __restrict__ bc1, long bc1Z, float alpha)
{
    __shared__ _Float16 As[128 * 64];
    __shared__ _Float16 Bs[128 * 64];

    const int L  = xcd_swz(blockIdx.x, gridDim.x);
    const int z  = L / perZ;
    const int r0 = L - z * perZ;
    const int zb = z / sk;
    const int zk = z - zb * sk;
    A += (long)zb * aZ + (long)zk * aK;
    B += (long)zb * bZ + (long)zk * bK;
    C += (long)z * cZ;
    const float* pc1 = (BIAS == 1) ? bc1 + (long)zb * bc1Z : nullptr;

    const int tileM = (r0 / tilesX) * 128;
    const int tileN = (r0 % tilesX) * 128;
    const int tid   = threadIdx.x;
    const int lane  = tid & 63;
    const int wave  = tid >> 6;
    const int wm    = (wave >> 1) * 64;
    const int wn    = (wave & 1) * 64;
    const int srow  = tid >> 3;
    const int sslot = tid & 7;

    f4 acc[4][4] = {};
    const int arow = lane & 15;
    const int kg   = lane >> 4;

    for (int k0 = 0; k0 < K; k0 += 64) {
        #pragma unroll
        for (int i = 0; i < 4; ++i) {
            const int row   = i * 32 + srow;
            const int gslot = sslot ^ (row & 7);
            gload_lds16(&A[(long)(tileM + row) * lda + k0 + gslot * 8],
                        &As[row * 64 + sslot * 8]);
            gload_lds16(&B[(long)(tileN + row) * ldb + k0 + gslot * 8],
                        &Bs[row * 64 + sslot * 8]);
        }
        __syncthreads();

        #pragma unroll
        for (int kk = 0; kk < 64; kk += 32) {
            h8 af[4], bf[4];
            #pragma unroll
            for (int m = 0; m < 4; ++m) {
                const int rr   = wm + m * 16 + arow;
                const int slot = (kk >> 3) + kg;
                af[m] = *(const h8*)&As[rr * 64 + ((slot ^ (rr & 7)) << 3)];
            }
            #pragma unroll
            for (int n = 0; n < 4; ++n) {
                const int rr   = wn + n * 16 + arow;
                const int slot = (kk >> 3) + kg;
                bf[n] = *(const h8*)&Bs[rr * 64 + ((slot ^ (rr & 7)) << 3)];
            }
            #pragma unroll
            for (int m = 0; m < 4; ++m)
                #pragma unroll
                for (int n = 0; n < 4; ++n)
                    acc[m][n] = __builtin_amdgcn_mfma_f32_16x16x32_f16(
                        af[m], bf[n], acc[m][n], 0, 0, 0);
        }
        __syncthreads();
    }

    #pragma unroll
    for (int m = 0; m < 4; ++m) {
        #pragma unroll
        for (int n = 0; n < 4; ++n) {
            const int col = tileN + wn + n * 16 + arow;
            #pragma unroll
            for (int j = 0; j < 4; ++j) {
                const int row = tileM + wm + m * 16 + (lane >> 4) * 4 + j;
                float v = acc[m][n][j] * alpha;
                if (BIAS == 1) v += pc1[col];
                C[(long)row * ldc + col] = (OutT)v;
            }
        }
    }
}

// 64x64 NT GEMM for the 1024^3 chain (occupancy-oriented: 1024 blocks).
// BIAS: 0 none; 3: + beta*(bc1[col]*br1[row] + bc2[col]*br2[row])
template<int BIAS>
__global__ __launch_bounds__(256) void gemm64(
    const _Float16* __restrict__ A, const _Float16* __restrict__ B,
    _Float16* __restrict__ C,
    int K, int lda, int ldb, int ldc, int tilesX, int perZ,
    long aZ, long bZ, long cZ,
    const float* __restrict__ bc1, long bc1Z,
    const float* __restrict__ br1, long br1Z,
    const float* __restrict__ bc2, long bc2Z,
    const float* __restrict__ br2, long br2Z,
    float beta)
{
    __shared__ _Float16 As[64 * 64];
    __shared__ _Float16 Bs[64 * 64];

    const int L  = xcd_swz(blockIdx.x, gridDim.x);
    const int z  = L / perZ;
    const int r0 = L - z * perZ;
    A += (long)z * aZ;
    B += (long)z * bZ;
    C += (long)z * cZ;
    const float* pc1 = nullptr; const float* pr1 = nullptr;
    const float* pc2 = nullptr; const float* pr2 = nullptr;
    if (BIAS == 3) {
        pc1 = bc1 + (long)z * bc1Z; pr1 = br1 + (long)z * br1Z;
        pc2 = bc2 + (long)z * bc2Z; pr2 = br2 + (long)z * br2Z;
    }

    const int tileM = (r0 / tilesX) * 64;
    const int tileN = (r0 % tilesX) * 64;
    const int tid   = threadIdx.x;
    const int lane  = tid & 63;
    const int wave  = tid >> 6;
    const int wm    = (wave >> 1) * 32;
    const int wn    = (wave & 1) * 32;
    const int srow  = tid >> 3;   // 0..31
    const int sslot = tid & 7;

    f4 acc[2][2] = {};
    const int arow = lane & 15;
    const int kg   = lane >> 4;

    for (int k0 = 0; k0 < K; k0 += 64) {
        #pragma unroll
        for (int i = 0; i < 2; ++i) {
            const int row   = i * 32 + srow;
            const int gslot = sslot ^ (row & 7);
            gload_lds16(&A[(long)(tileM + row) * lda + k0 + gslot * 8],
                        &As[row * 64 + sslot * 8]);
            gload_lds16(&B[(long)(tileN + row) * ldb + k0 + gslot * 8],
                        &Bs[row * 64 + sslot * 8]);
        }
        __syncthreads();

        #pragma unroll
        for (int kk = 0; kk < 64; kk += 32) {
            h8 af[2], bf[2];
            #pragma unroll
            for (int m = 0; m < 2; ++m) {
                const int rr   = wm + m * 16 + arow;
                const int slot = (kk >> 3) + kg;
                af[m] = *(const h8*)&As[rr * 64 + ((slot ^ (rr & 7)) << 3)];
            }
            #pragma unroll
            for (int n = 0; n < 2; ++n) {
                const int rr   = wn + n * 16 + arow;
                const int slot = (kk >> 3) + kg;
                bf[n] = *(const h8*)&Bs[rr * 64 + ((slot ^ (rr & 7)) << 3)];
            }
            #pragma unroll
            for (int m = 0; m < 2; ++m)
                #pragma unroll
                for (int n = 0; n < 2; ++n)
                    acc[m][n] = __builtin_amdgcn_mfma_f32_16x16x32_f16(
                        af[m], bf[n], acc[m][n], 0, 0, 0);
        }
        __syncthreads();
    }

    #pragma unroll
    for (int m = 0; m < 2; ++m) {
        #pragma unroll
        for (int n = 0; n < 2; ++n) {
            const int col = tileN + wn + n * 16 + arow;
            #pragma unroll
            for (int j = 0; j < 4; ++j) {
                const int row = tileM + wm + m * 16 + (lane >> 4) * 4 + j;
                float v = acc[m][n][j];
                if (BIAS == 3) v += beta * (pc1[col] * pr1[row] + pc2[col] * pr2[row]);
                C[(long)row * ldc + col] = (_Float16)v;
            }
        }
    }
}

extern "C" void kernel_launch(void* const* d_in, const int* in_sizes, int n_in,
                              void* d_out, int out_size, void* d_ws, size_t ws_size,
                              hipStream_t stream)
{
    const float* x  = (const float*)d_in[0];
    const float* Wq = (const float*)d_in[1];
    const float* bq = (const float*)d_in[2];
    const float* Wk = (const float*)d_in[3];
    const float* bk = (const float*)d_in[4];
    const float* Wv = (const float*)d_in[5];
    const float* bv = (const float*)d_in[6];
    float* out = (float*)d_out;

    const long DD = (long)DM * DM;
    const long DS = (long)DM * SEQ;

    // ws: [xh 32MB][xt 32MB -> Gh|Ph|KVth|Rth][Wqt 2MB][Wkh 2MB][Wvh 2MB][xs u2 w cv]
    char* base = (char*)d_ws;
    _Float16* xh   = (_Float16*)base;
    _Float16* xt   = (_Float16*)(base + 32l * 1024 * 1024);
    _Float16* Gh   = xt;
    _Float16* Ph   = xt + 4l * 1024 * 1024;
    _Float16* KVth = xt + 8l * 1024 * 1024;
    _Float16* Rth  = xt + 12l * 1024 * 1024;
    _Float16* Wqt  = (_Float16*)(base + 64l * 1024 * 1024);
    _Float16* Wkh  = Wqt + DD;
    _Float16* Wvh  = Wkh + DD;
    float*    xs   = (float*)(Wvh + DD);   // [4][1024]
    float*    u2   = xs + 4 * 1024;        // [4][1024]
    float*    w    = u2 + 4 * 1024;        // [4][1024] (contiguous after u2!)
    float*    cv   = w + 4 * 1024;         // [4][1024]
    _Float16* parts = (_Float16*)d_out;    // [16][1024][1024] fp16 scratch (32MB)

    // 1) converts / transposes
    cvt_transpose<true ><<<dim3(16, 64, 4), 256, 0, stream>>>(x,  xt,  xh, SEQ, DM);
    cvt_transpose<false><<<dim3(16, 16, 1), 256, 0, stream>>>(Wq, Wqt, nullptr, DM, DM);
    cvt_pair<<<2048, 256, 0, stream>>>(Wk, Wkh, Wv, Wvh);

    // 2) xs = rowsum(xt)
    rowsum_xt<<<1024, 256, 0, stream>>>(xt, xs);

    // 3) u2 = Wv.xs + 4096*bv ; w = Wk.xs   (one launch, dst = u2 base)
    gemv_dual<<<2048, 256, 0, stream>>>(Wvh, Wkh, xs, bv, u2);

    // 4) Gram split-K=4: parts[b*4+k] = xt-slice @ xt-slice^T  (fp16 partials)
    gemm_nt<_Float16, 0><<<1024, 256, 0, stream>>>(
        xt, xt, parts, 1024, SEQ, SEQ, DM, 8, 64,
        DS, DS, DD, 4, 1024, 1024, nullptr, 0, 1.0f);

    // 5) Gh = (1/32)*sum parts
    reduce_gh<<<2048, 256, 0, stream>>>(parts, Gh);

    // 6) Ph[b] = Wv . Gh[b]^T-contract   (NT: A=Wvh, B=Gh rows)
    gemm64<0><<<1024, 256, 0, stream>>>(
        Wvh, Gh, Ph, 1024, DM, DM, DM, 16, 256,
        0, DD, DD, nullptr, 0, nullptr, 0, nullptr, 0, nullptr, 0, 0.f);

    // 7) KVth[b] = Ph . Wk^T + (1/32)(bk[col]*u2[row] + w[col]*bv[row])
    gemm64<3><<<1024, 256, 0, stream>>>(
        Ph, Wkh, KVth, 1024, DM, DM, DM, 16, 256,
        DD, 0, DD, bk, 0, u2, 1024, w, 1024, bv, 0, 0.03125f);

    // 8) cv[b][e] = sum_d bq[d]*KVth[b][e][d]
    gemv_k1024<<<1024, 256, 0, stream>>>(KVth, DD, bq, cv);

    // 9) Rth[b] = KVth . Wq^T (via Wqt)
    gemm64<0><<<1024, 256, 0, stream>>>(
        KVth, Wqt, Rth, 1024, DM, DM, DM, 16, 256,
        DD, 0, DD, nullptr, 0, nullptr, 0, nullptr, 0, nullptr, 0, 0.f);

    // 10) E[b] = xh . Rth^T + cv   -> fp32 out (overwrites parts scratch)
    gemm_nt<float, 1><<<1024, 256, 0, stream>>>(
        xh, Rth, out, 1024, DM, DM, DM, 8, 256,
        DS, DD, DS, 1, 0, 0, cv, 1024, 1.0f);
}